// Round 1
// baseline (184.434 us; speedup 1.0000x reference)
//
#include <hip/hip_runtime.h>
#include <hip/hip_bf16.h>

using short8 = __attribute__((ext_vector_type(8))) short;
using f32x4  = __attribute__((ext_vector_type(4))) float;

#define MBATCH 16
#define NUMV   128
#define LEN    64
#define SZ     256
#define HPAD   264   // 256 + 8 shorts pad -> row stride 528 B, banks step 4 -> 2-way (free)

__device__ __forceinline__ unsigned short bfbits(float x) {
  union { float f; unsigned u; } c; c.f = x;
  unsigned r = c.u + 0x7FFFu + ((c.u >> 16) & 1u);   // RNE f32->bf16
  return (unsigned short)(r >> 16);
}

// ---------------- prep 1: u[bn][s], v[bn][s] (layer-1 factorization) ----------------
// u = x[b,n] @ W1[0:65],  v = x[b,n] @ W1[65:130] + b1, coord channel = n
__global__ void uv_prep(const float* __restrict__ in_, const float* __restrict__ W1,
                        const float* __restrict__ b1,
                        float* __restrict__ u, float* __restrict__ v) {
  int bn = blockIdx.x;                 // b*128 + n
  int n  = bn & (NUMV - 1);
  int s  = threadIdx.x;                // 256 threads
  __shared__ float xs[LEN];
  if (s < LEN) xs[s] = in_[bn * LEN + s];
  __syncthreads();
  float fn = (float)n;
  float uu = fn * W1[64 * SZ + s];
  float vv = fn * W1[129 * SZ + s] + b1[s];
  for (int c = 0; c < LEN; ++c) {
    uu = fmaf(xs[c], W1[c * SZ + s], uu);
    vv = fmaf(xs[c], W1[(65 + c) * SZ + s], vv);
  }
  u[bn * SZ + s] = uu;
  v[bn * SZ + s] = vv;
}

// ---------------- prep 2: W2/W3/W4 -> bf16, transposed, fragment-ordered, bank-swizzled ----
// wlay[L][kb][slot'] : slot = 4*c + q, slot' = slot ^ (c&7); 16B at slot' holds
// Wt[c][kb*32 + q*8 .. +7] = W[kb*32+q*8+i][c].  (c = output channel, kb = K-chunk of 32)
__global__ void w_prep(const float* __restrict__ W2, const float* __restrict__ W3,
                       const float* __restrict__ W4, short* __restrict__ wlay) {
  int L = blockIdx.x >> 3, kb = blockIdx.x & 7;     // 24 blocks
  const float* W = (L == 0) ? W2 : (L == 1) ? W3 : W4;
  int c = threadIdx.x;                              // 256 threads
  short* dst = wlay + L * 65536 + kb * 8192;
  for (int qq = 0; qq < 4; ++qq) {
    short8 pk;
    for (int i = 0; i < 8; ++i)
      pk[i] = (short)bfbits(W[(kb * 32 + qq * 8 + i) * SZ + c]);
    int slot = (c * 4 + qq) ^ (c & 7);
    *reinterpret_cast<short8*>(dst + slot * 8) = pk;
  }
}

// ---------------- main fused kernel ----------------
// One WG per (b, a): 128 rows (all j), 512 threads = 8 waves (wM in 0..3 covers 256 out-ch,
// wN in 0..1 covers 128 rows; each wave 64x64 tile, 4x4 fragments of 16x16x32 bf16 MFMA).
__global__ __launch_bounds__(512) void fused_mlp(
    const float* __restrict__ u, const float* __restrict__ v,
    const short* __restrict__ wlay,
    const float* __restrict__ b2, const float* __restrict__ b3, const float* __restrict__ b4,
    float* __restrict__ partial) {
  __shared__ __align__(16) short hbuf[128 * HPAD];   // 67584 B, h row-major [row][k]
  __shared__ __align__(16) short wbuf[2 * 8192];     // 2 x 16 KB Wt K-chunks
  __shared__ float pbuf[512];

  int wg = blockIdx.x;
  int b = wg >> 7, a = wg & (NUMV - 1);
  int tid = threadIdx.x;

  // ---- h1 = relu(u[b,j] + v[b,a] + b1) -> bf16, row-major in LDS ----
  const float2* ub = (const float2*)(u + (size_t)b * NUMV * SZ);
  const float2* vb = (const float2*)(v + ((size_t)b * NUMV + a) * SZ);
  for (int it = 0; it < 32; ++it) {
    int flat2 = tid + it * 512;          // pair index over 128*128
    int j = flat2 >> 7, sp = flat2 & 127;
    float2 uu = ub[j * 128 + sp];
    float2 vv = vb[sp];
    float h0 = fmaxf(uu.x + vv.x, 0.f);
    float h1 = fmaxf(uu.y + vv.y, 0.f);
    unsigned pack = ((unsigned)bfbits(h1) << 16) | (unsigned)bfbits(h0);
    *reinterpret_cast<unsigned*>(&hbuf[j * HPAD + sp * 2]) = pack;
  }

  int wave = tid >> 6, lane = tid & 63;
  int l16 = lane & 15, q = lane >> 4;
  int wM = wave & 3, wN = wave >> 2;

  const float* biases[3] = { b2, b3, b4 };
  __syncthreads();

  for (int L = 0; L < 3; ++L) {
    const short* wl = wlay + L * 65536;

    // epilogue bias: s' = wM*64 + m*16 + q*4 + reg
    f32x4 biasv[4];
    for (int m = 0; m < 4; ++m)
      biasv[m] = *reinterpret_cast<const f32x4*>(biases[L] + wM * 64 + m * 16 + q * 4);

    f32x4 acc[4][4];
    for (int m = 0; m < 4; ++m)
      for (int n = 0; n < 4; ++n)
        acc[m][n] = f32x4{0.f, 0.f, 0.f, 0.f};

    // stage K-chunk 0 (16 KB): 512 threads x 32 B
    {
      const short8* g = reinterpret_cast<const short8*>(wl) + tid * 2;
      short8 t0 = g[0], t1 = g[1];
      short8* d = reinterpret_cast<short8*>(wbuf) + tid * 2;
      d[0] = t0; d[1] = t1;
    }
    __syncthreads();

    for (int kb = 0; kb < 8; ++kb) {
      int cur = kb & 1;
      short8 t0, t1;
      bool pf = (kb < 7);
      if (pf) {   // issue next-chunk loads early (hide under MFMA)
        const short8* g = reinterpret_cast<const short8*>(wl + (kb + 1) * 8192) + tid * 2;
        t0 = g[0]; t1 = g[1];
      }
      // A-frags: Wt[s'][kb*32 + q*8 ..] from swizzled wbuf
      short8 af[4], bfr[4];
      const short* wb = wbuf + cur * 8192;
      for (int m = 0; m < 4; ++m) {
        int sp = wM * 64 + m * 16 + l16;
        int slot = (sp * 4 + q) ^ (sp & 7);
        af[m] = *reinterpret_cast<const short8*>(wb + slot * 8);
      }
      // B-frags: h[row][kb*32 + q*8 ..]
      for (int n = 0; n < 4; ++n) {
        int row = wN * 64 + n * 16 + l16;
        bfr[n] = *reinterpret_cast<const short8*>(&hbuf[row * HPAD + kb * 32 + q * 8]);
      }
      for (int m = 0; m < 4; ++m)
        for (int n = 0; n < 4; ++n)
          acc[m][n] = __builtin_amdgcn_mfma_f32_16x16x32_bf16(af[m], bfr[n], acc[m][n], 0, 0, 0);
      if (pf) {
        short8* d = reinterpret_cast<short8*>(wbuf + (cur ^ 1) * 8192) + tid * 2;
        d[0] = t0; d[1] = t1;
      }
      __syncthreads();
    }

    if (L < 2) {
      // write h_next[row][s'] : 4 consecutive out-channels per lane -> one b64 per frag
      for (int m = 0; m < 4; ++m) {
        int sb = wM * 64 + m * 16 + q * 4;
        for (int n = 0; n < 4; ++n) {
          int row = wN * 64 + n * 16 + l16;
          f32x4 t = acc[m][n];
          unsigned lo = (unsigned)bfbits(fmaxf(t[0] + biasv[m][0], 0.f))
                      | ((unsigned)bfbits(fmaxf(t[1] + biasv[m][1], 0.f)) << 16);
          unsigned hi = (unsigned)bfbits(fmaxf(t[2] + biasv[m][2], 0.f))
                      | ((unsigned)bfbits(fmaxf(t[3] + biasv[m][3], 0.f)) << 16);
          uint2 pk; pk.x = lo; pk.y = hi;
          *reinterpret_cast<uint2*>(&hbuf[row * HPAD + sb]) = pk;
        }
      }
      __syncthreads();
    } else {
      // final layer: relu + bias, reduce over the WG's 128 rows
      float ps[4][4];
      for (int m = 0; m < 4; ++m)
        for (int r = 0; r < 4; ++r) {
          float s = 0.f;
          for (int n = 0; n < 4; ++n)
            s += fmaxf(acc[m][n][r] + biasv[m][r], 0.f);
          ps[m][r] = s;
        }
      for (int m = 0; m < 4; ++m)
        for (int r = 0; r < 4; ++r) {
          float x = ps[m][r];
          x += __shfl_xor(x, 1);
          x += __shfl_xor(x, 2);
          x += __shfl_xor(x, 4);
          x += __shfl_xor(x, 8);
          ps[m][r] = x;
        }
      if (l16 == 0) {
        for (int m = 0; m < 4; ++m)
          for (int r = 0; r < 4; ++r)
            pbuf[wN * 256 + wM * 64 + m * 16 + q * 4 + r] = ps[m][r];
      }
      __syncthreads();
      if (tid < 256)
        partial[(size_t)wg * SZ + tid] = pbuf[tid] + pbuf[256 + tid];
    }
  }
}

// ---------------- final reduction over a ----------------
__global__ void reduce_partials(const float* __restrict__ partial, float* __restrict__ out) {
  int b = blockIdx.x;            // 16 blocks x 256 threads
  int s = threadIdx.x;
  const float* p = partial + (size_t)b * NUMV * SZ + s;
  float acc = 0.f;
  for (int a = 0; a < NUMV; ++a) acc += p[(size_t)a * SZ];
  out[b * SZ + s] = acc;
}

extern "C" void kernel_launch(void* const* d_in, const int* in_sizes, int n_in,
                              void* d_out, int out_size, void* d_ws, size_t ws_size,
                              hipStream_t stream) {
  const float* in_ = (const float*)d_in[0];
  const float* W1  = (const float*)d_in[1];
  const float* b1  = (const float*)d_in[2];
  const float* W2  = (const float*)d_in[3];
  const float* b2  = (const float*)d_in[4];
  const float* W3  = (const float*)d_in[5];
  const float* b3  = (const float*)d_in[6];
  const float* W4  = (const float*)d_in[7];
  const float* b4  = (const float*)d_in[8];
  float* out = (float*)d_out;

  char* ws = (char*)d_ws;
  float* u       = (float*)(ws);                       // 2 MB
  float* v       = (float*)(ws + (2u << 20));          // 2 MB
  short* wlay    = (short*)(ws + (4u << 20));          // 384 KB
  float* partial = (float*)(ws + (4u << 20) + (1u << 19));  // 2 MB

  uv_prep<<<MBATCH * NUMV, 256, 0, stream>>>(in_, W1, b1, u, v);
  w_prep<<<24, 256, 0, stream>>>(W2, W3, W4, wlay);
  fused_mlp<<<MBATCH * NUMV, 512, 0, stream>>>(u, v, wlay, b2, b3, b4, partial);
  reduce_partials<<<MBATCH, 256, 0, stream>>>(partial, out);
}

// Round 2
// 183.066 us; speedup vs baseline: 1.0075x; 1.0075x over previous
//
#include <hip/hip_runtime.h>
#include <hip/hip_bf16.h>

using short8 = __attribute__((ext_vector_type(8))) short;
using f32x4  = __attribute__((ext_vector_type(4))) float;

#define MBATCH 16
#define NUMV   128
#define LEN    64
#define SZ     256
#define ROWS   64    // j-rows per workgroup (half of NUMV)
#define HPAD   264   // row stride in shorts: 528 B -> conflict-free frag reads

__device__ __forceinline__ unsigned short bfbits(float x) {
  union { float f; unsigned u; } c; c.f = x;
  unsigned r = c.u + 0x7FFFu + ((c.u >> 16) & 1u);   // RNE f32->bf16
  return (unsigned short)(r >> 16);
}

typedef const unsigned char __attribute__((address_space(1))) gu8;
typedef unsigned char __attribute__((address_space(3))) lu8;
__device__ __forceinline__ void gload_lds16(const void* g, void* l) {
  // dest = (wave-uniform l) + lane*16 ; src = per-lane g
  __builtin_amdgcn_global_load_lds((gu8*)g, (lu8*)l, 16, 0, 0);
}

// ---------------- prep 1: u[bn][s], v[bn][s] (layer-1 factorization) ----------------
__global__ void uv_prep(const float* __restrict__ in_, const float* __restrict__ W1,
                        const float* __restrict__ b1,
                        float* __restrict__ u, float* __restrict__ v) {
  int bn = blockIdx.x;
  int n  = bn & (NUMV - 1);
  int s  = threadIdx.x;                // 256 threads
  __shared__ float xs[LEN];
  if (s < LEN) xs[s] = in_[bn * LEN + s];
  __syncthreads();
  float fn = (float)n;
  float uu = fn * W1[64 * SZ + s];
  float vv = fn * W1[129 * SZ + s] + b1[s];
  for (int c = 0; c < LEN; ++c) {
    uu = fmaf(xs[c], W1[c * SZ + s], uu);
    vv = fmaf(xs[c], W1[(65 + c) * SZ + s], vv);
  }
  u[bn * SZ + s] = uu;
  v[bn * SZ + s] = vv;
}

// ---------------- prep 2: W2/W3/W4 -> bf16, transposed, fragment-ordered, bank-swizzled ----
// wlay[L][kb][slot'] : slot = 4*c + q, slot' = slot ^ (c&7); 16B at slot' holds
// Wt[c][kb*32 + q*8 .. +7].  Linear layout == exactly what global_load_lds stages.
__global__ void w_prep(const float* __restrict__ W2, const float* __restrict__ W3,
                       const float* __restrict__ W4, short* __restrict__ wlay) {
  int L = blockIdx.x >> 3, kb = blockIdx.x & 7;     // 24 blocks
  const float* W = (L == 0) ? W2 : (L == 1) ? W3 : W4;
  int c = threadIdx.x;                              // 256 threads
  short* dst = wlay + L * 65536 + kb * 8192;
  for (int qq = 0; qq < 4; ++qq) {
    short8 pk;
    for (int i = 0; i < 8; ++i)
      pk[i] = (short)bfbits(W[(kb * 32 + qq * 8 + i) * SZ + c]);
    int slot = (c * 4 + qq) ^ (c & 7);
    *reinterpret_cast<short8*>(dst + slot * 8) = pk;
  }
}

// ---------------- main fused kernel ----------------
// One WG per (b, a, jhalf): 64 rows, 512 threads = 8 waves.
// wM in 0..3 -> 64 out-channels each; wN in 0..1 -> 32 rows each.
// LDS = 33792 (hbuf) + 32768 (wbuf dbuf) + 2048 (pbuf) = 68608 B -> 2 blocks/CU.
__global__ __launch_bounds__(512, 4) void fused_mlp(
    const float* __restrict__ u, const float* __restrict__ v,
    const short* __restrict__ wlay,
    const float* __restrict__ b2, const float* __restrict__ b3, const float* __restrict__ b4,
    float* __restrict__ partial) {
  __shared__ __align__(16) short hbuf[ROWS * HPAD];
  __shared__ __align__(16) short wbuf[2 * 8192];
  __shared__ float pbuf[512];

  int wg = blockIdx.x;
  int b = wg >> 8, a = (wg >> 1) & 127, jh = wg & 1;
  int tid = threadIdx.x;

  // ---- h1 = relu(u[b,j] + v[b,a] + b1) -> bf16, row-major in LDS ----
  const float2* ub = (const float2*)(u + (size_t)b * NUMV * SZ) + jh * ROWS * 128;
  const float2* vb = (const float2*)(v + ((size_t)b * NUMV + a) * SZ);
  for (int it = 0; it < 16; ++it) {
    int flat2 = tid + it * 512;          // pair index over 64*128
    int jr = flat2 >> 7, sp = flat2 & 127;
    float2 uu = ub[jr * 128 + sp];
    float2 vv = vb[sp];
    float h0 = fmaxf(uu.x + vv.x, 0.f);
    float h1 = fmaxf(uu.y + vv.y, 0.f);
    unsigned pack = ((unsigned)bfbits(h1) << 16) | (unsigned)bfbits(h0);
    *reinterpret_cast<unsigned*>(&hbuf[jr * HPAD + sp * 2]) = pack;
  }

  int wave = tid >> 6, lane = tid & 63;
  int l16 = lane & 15, q = lane >> 4;
  int wM = wave & 3, wN = wave >> 2;

  const float* biases[3] = { b2, b3, b4 };
  __syncthreads();

  for (int L = 0; L < 3; ++L) {
    const char* wl = (const char*)(wlay + L * 65536);

    f32x4 biasv[4];
    for (int m = 0; m < 4; ++m)
      biasv[m] = *reinterpret_cast<const f32x4*>(biases[L] + wM * 64 + m * 16 + q * 4);

    f32x4 acc[4][2];
    for (int m = 0; m < 4; ++m)
      for (int n = 0; n < 2; ++n)
        acc[m][n] = f32x4{0.f, 0.f, 0.f, 0.f};

    // stage K-chunk 0 (16 KB) direct global->LDS: 8 waves x 2 KB
    {
      const char* g = wl + wave * 2048 + lane * 16;
      char* d = (char*)wbuf + wave * 2048;
      gload_lds16(g, d);
      gload_lds16(g + 1024, d + 1024);
    }
    __syncthreads();

    for (int kb = 0; kb < 8; ++kb) {
      int cur = kb & 1;
      // A-frags: Wt[s'][kb*32 + q*8 ..] from swizzled wbuf
      short8 af[4], bfr[2];
      const short* wb = wbuf + cur * 8192;
      for (int m = 0; m < 4; ++m) {
        int sp = wM * 64 + m * 16 + l16;
        int slot = (sp * 4 + q) ^ (sp & 7);
        af[m] = *reinterpret_cast<const short8*>(wb + slot * 8);
      }
      // B-frags: h[row][kb*32 + q*8 ..]
      for (int n = 0; n < 2; ++n) {
        int row = wN * 32 + n * 16 + l16;
        bfr[n] = *reinterpret_cast<const short8*>(&hbuf[row * HPAD + kb * 32 + q * 8]);
      }
      // prefetch next chunk straight into the other LDS buffer (drained by barrier)
      if (kb < 7) {
        const char* g = wl + (kb + 1) * 16384 + wave * 2048 + lane * 16;
        char* d = (char*)wbuf + (cur ^ 1) * 16384 + wave * 2048;
        gload_lds16(g, d);
        gload_lds16(g + 1024, d + 1024);
      }
      __builtin_amdgcn_s_setprio(1);
      for (int m = 0; m < 4; ++m)
        for (int n = 0; n < 2; ++n)
          acc[m][n] = __builtin_amdgcn_mfma_f32_16x16x32_bf16(af[m], bfr[n], acc[m][n], 0, 0, 0);
      __builtin_amdgcn_s_setprio(0);
      __syncthreads();
    }

    if (L < 2) {
      // h_next[row][s'] : 4 consecutive out-channels per lane -> one 8B store per frag
      for (int m = 0; m < 4; ++m) {
        int sb = wM * 64 + m * 16 + q * 4;
        for (int n = 0; n < 2; ++n) {
          int row = wN * 32 + n * 16 + l16;
          f32x4 t = acc[m][n];
          unsigned lo = (unsigned)bfbits(fmaxf(t[0] + biasv[m][0], 0.f))
                      | ((unsigned)bfbits(fmaxf(t[1] + biasv[m][1], 0.f)) << 16);
          unsigned hi = (unsigned)bfbits(fmaxf(t[2] + biasv[m][2], 0.f))
                      | ((unsigned)bfbits(fmaxf(t[3] + biasv[m][3], 0.f)) << 16);
          uint2 pk; pk.x = lo; pk.y = hi;
          *reinterpret_cast<uint2*>(&hbuf[row * HPAD + sb]) = pk;
        }
      }
      __syncthreads();
    } else {
      // final layer: relu + bias, reduce over the WG's 64 rows
      float ps[4][4];
      for (int m = 0; m < 4; ++m)
        for (int r = 0; r < 4; ++r) {
          float s = 0.f;
          for (int n = 0; n < 2; ++n)
            s += fmaxf(acc[m][n][r] + biasv[m][r], 0.f);
          ps[m][r] = s;
        }
      for (int m = 0; m < 4; ++m)
        for (int r = 0; r < 4; ++r) {
          float x = ps[m][r];
          x += __shfl_xor(x, 1);
          x += __shfl_xor(x, 2);
          x += __shfl_xor(x, 4);
          x += __shfl_xor(x, 8);
          ps[m][r] = x;
        }
      if (l16 == 0) {
        for (int m = 0; m < 4; ++m)
          for (int r = 0; r < 4; ++r)
            pbuf[wN * 256 + wM * 64 + m * 16 + q * 4 + r] = ps[m][r];
      }
      __syncthreads();
      if (tid < 256)
        partial[(size_t)wg * SZ + tid] = pbuf[tid] + pbuf[256 + tid];
    }
  }
}

// ---------------- final reduction over (a, jhalf) ----------------
__global__ void reduce_partials(const float* __restrict__ partial, float* __restrict__ out) {
  int b = blockIdx.x;            // 16 blocks x 256 threads
  int s = threadIdx.x;
  const float* p = partial + (size_t)b * 256 * SZ + s;
  float acc = 0.f;
  for (int i = 0; i < 256; ++i) acc += p[(size_t)i * SZ];
  out[b * SZ + s] = acc;
}

extern "C" void kernel_launch(void* const* d_in, const int* in_sizes, int n_in,
                              void* d_out, int out_size, void* d_ws, size_t ws_size,
                              hipStream_t stream) {
  const float* in_ = (const float*)d_in[0];
  const float* W1  = (const float*)d_in[1];
  const float* b1  = (const float*)d_in[2];
  const float* W2  = (const float*)d_in[3];
  const float* b2  = (const float*)d_in[4];
  const float* W3  = (const float*)d_in[5];
  const float* b3  = (const float*)d_in[6];
  const float* W4  = (const float*)d_in[7];
  const float* b4  = (const float*)d_in[8];
  float* out = (float*)d_out;

  char* ws = (char*)d_ws;
  float* u       = (float*)(ws);                                 // 2 MB
  float* v       = (float*)(ws + (2u << 20));                    // 2 MB
  short* wlay    = (short*)(ws + (4u << 20));                    // 384 KB
  float* partial = (float*)(ws + (4u << 20) + (1u << 19));       // 4 MB

  uv_prep<<<MBATCH * NUMV, 256, 0, stream>>>(in_, W1, b1, u, v);
  w_prep<<<24, 256, 0, stream>>>(W2, W3, W4, wlay);
  fused_mlp<<<MBATCH * NUMV * 2, 512, 0, stream>>>(u, v, wlay, b2, b3, b4, partial);
  reduce_partials<<<MBATCH, 256, 0, stream>>>(partial, out);
}